// Round 1
// baseline (1682.995 us; speedup 1.0000x reference)
//
#include <hip/hip_runtime.h>
#include <hip/hip_fp16.h>
#include <cstdint>

typedef _Float16 f16;
typedef _Float16 f16x2 __attribute__((ext_vector_type(2)));
typedef _Float16 f16x8 __attribute__((ext_vector_type(8)));
typedef float f32x4 __attribute__((ext_vector_type(4)));

#define kH 200
#define kG 800
#define kS 255
#define kW 512
#define kMid 127
#define NT 832           // 13 waves: 800 gate threads + 32 pad

// ---- ws layout (byte offsets), total ~213 MB ----
#define OFF_WF   209715200ULL   // 8 x [800x200] f16 weight matrices
#define OFF_BS   212275200ULL   // 4 x [800] f32 combined biases
#define OFF_SENT 212288000ULL   // [255x200] f32 sentence embeddings
#define OFF_XPP  212492032ULL   // 2 x [128x800] f16 prev/post preactivations
#define OFF_OUTS 212901632ULL   // [400] f32 prev_out|post_out

__device__ __forceinline__ float fdot2f(uint32_t a, uint32_t b, float c) {
  return __builtin_amdgcn_fdot2(__builtin_bit_cast(f16x2, a),
                                __builtin_bit_cast(f16x2, b), c, false);
}
__device__ __forceinline__ uint32_t packh2(float a, float b) {
  f16x2 v; v[0] = (f16)a; v[1] = (f16)b;
  return __builtin_bit_cast(uint32_t, v);
}
__device__ __forceinline__ float sigf(float x) { return 1.0f / (1.0f + __expf(-x)); }
__device__ __forceinline__ float tanhf_(float x) { return 1.0f - 2.0f / (__expf(2.0f * x) + 1.0f); }

// ---------------- prep: f32->f16 weights, combined biases ----------------
__global__ __launch_bounds__(256) void ABHUE_prep(
    const float* W0, const float* W1, const float* W2, const float* W3,
    const float* W4, const float* W5, const float* W6, const float* W7,
    const float* B0i, const float* B0h, const float* B1i, const float* B1h,
    const float* B2i, const float* B2h, const float* B3i, const float* B3h,
    f16* wdst, float* bdst)
{
  int idx = blockIdx.x * 256 + threadIdx.x;
  const int WN = kG * kH;  // 160000
  if (idx < 8 * WN) {
    int m = idx / WN, off = idx % WN;
    const float* src = m == 0 ? W0 : m == 1 ? W1 : m == 2 ? W2 : m == 3 ? W3
                     : m == 4 ? W4 : m == 5 ? W5 : m == 6 ? W6 : W7;
    wdst[idx] = (f16)src[off];
  } else {
    int j = idx - 8 * WN;
    if (j < 4 * kG) {
      int st = j / kG, k = j % kG;
      const float* bi = st == 0 ? B0i : st == 1 ? B1i : st == 2 ? B2i : B3i;
      const float* bh = st == 0 ? B0h : st == 1 ? B1h : st == 2 ? B2h : B3h;
      bdst[j] = bi[k] + bh[k];
    }
  }
}

// ---------------- GEMM: X[m, 0..799] = A[m,:200] @ W[800,200]^T + bias ----------------
// f16 MFMA 16x16x32; BM=64 rows/block, n-loop of 13 x 64-col tiles inside block.
#define BM 64
#define BKP 232   // LDS k-stride (f16): 464B = 29*16 -> ~2-way banks, 16B-aligned rows
__global__ __launch_bounds__(256) void ABHUE_gemm_x(
    const float* __restrict__ A, const f16* __restrict__ Wf,
    const float* __restrict__ bias, f16* __restrict__ X, int rev)
{
  __shared__ __align__(16) f16 Al[BM * BKP];
  __shared__ __align__(16) f16 Bl[BM * BKP];
  int tid = threadIdx.x;
  int m0 = blockIdx.x * BM;

  // zero the k-pad region [200,232) of both tiles (64 rows x 16 dwords)
  #pragma unroll
  for (int it = 0; it < 4; ++it) {
    int idx = tid + 256 * it;           // 0..1023
    int row = idx >> 4, dw = idx & 15;
    *(uint32_t*)(&Al[row * BKP + 200 + dw * 2]) = 0u;
    *(uint32_t*)(&Bl[row * BKP + 200 + dw * 2]) = 0u;
  }
  // stage A: 64 rows x 50 float4, convert f32->f16
  for (int it = 0; it < 13; ++it) {
    int q = tid + 256 * it;
    if (q < 3200) {
      int row = q / 50, c = q % 50;
      int rg = m0 + row; if (rev >= 0) rg = rev - rg;
      const float4 v = *(const float4*)(A + (size_t)rg * kH + c * 4);
      f16x2 p0; p0[0] = (f16)v.x; p0[1] = (f16)v.y;
      f16x2 p1; p1[0] = (f16)v.z; p1[1] = (f16)v.w;
      uint2 pk; pk.x = __builtin_bit_cast(uint32_t, p0); pk.y = __builtin_bit_cast(uint32_t, p1);
      *(uint2*)(&Al[row * BKP + c * 4]) = pk;
    }
  }
  int wv = tid >> 6, lane = tid & 63;
  int lr = lane & 15, lq = lane >> 4;

  for (int nt = 0; nt < 13; ++nt) {
    int n0 = nt * 64;
    __syncthreads();
    // stage B tile: Wf rows n0..n0+63 (f16, 25 x uint4 per row)
    for (int it = 0; it < 7; ++it) {
      int q = tid + 256 * it;
      if (q < 1600) {
        int row = q / 25, c = q % 25;
        int ng = n0 + row;
        uint4 v = (ng < kG) ? *(const uint4*)(Wf + (size_t)ng * kH + c * 8)
                            : make_uint4(0, 0, 0, 0);
        *(uint4*)(&Bl[row * BKP + c * 8]) = v;
      }
    }
    __syncthreads();
    f32x4 acc0 = {0,0,0,0}, acc1 = {0,0,0,0}, acc2 = {0,0,0,0}, acc3 = {0,0,0,0};
    #pragma unroll
    for (int ks = 0; ks < 7; ++ks) {
      int k0 = ks * 32 + lq * 8;
      f16x8 a  = *(const f16x8*)(&Al[(wv * 16 + lr) * BKP + k0]);
      f16x8 b0 = *(const f16x8*)(&Bl[( 0 + lr) * BKP + k0]);
      f16x8 b1 = *(const f16x8*)(&Bl[(16 + lr) * BKP + k0]);
      f16x8 b2 = *(const f16x8*)(&Bl[(32 + lr) * BKP + k0]);
      f16x8 b3 = *(const f16x8*)(&Bl[(48 + lr) * BKP + k0]);
      acc0 = __builtin_amdgcn_mfma_f32_16x16x32_f16(a, b0, acc0, 0, 0, 0);
      acc1 = __builtin_amdgcn_mfma_f32_16x16x32_f16(a, b1, acc1, 0, 0, 0);
      acc2 = __builtin_amdgcn_mfma_f32_16x16x32_f16(a, b2, acc2, 0, 0, 0);
      acc3 = __builtin_amdgcn_mfma_f32_16x16x32_f16(a, b3, acc3, 0, 0, 0);
    }
    auto epi = [&](f32x4 acc, int nn) {
      int col = n0 + nn * 16 + lr;
      if (col < kG) {
        float bv = bias[col];
        #pragma unroll
        for (int rr = 0; rr < 4; ++rr) {
          int m = m0 + wv * 16 + lq * 4 + rr;
          X[(size_t)m * kG + col] = (f16)(acc[rr] + bv);
        }
      }
    };
    epi(acc0, 0); epi(acc1, 1); epi(acc2, 2); epi(acc3, 3);
  }
}

// ---------------- sequential LSTM core (one block = one sequence) ----------------
// Whh f16: k 0..119 in VGPRs (15 x uint4/thread), k 120..199 in LDS (pair-interleaved).
// h kept as packed-f16 pairs in LDS; gates/cell fp32. X preactivations include bias.
static __device__ void lstm_core(const f16* __restrict__ X, const f16* __restrict__ Whh,
                                 const float* __restrict__ h0, int nsteps,
                                 float* __restrict__ out)
{
  __shared__ __align__(16) uint2 wl[20 * 800];   // wl[j2*800+r]: f16 k = 120+4*j2 .. +3 of row r
  __shared__ float gsh[kG];
  __shared__ __align__(16) uint32_t hpk[100];
  int tid = threadIdx.x;

  for (int it = 0; it < 20; ++it) {
    int idx = tid + NT * it;
    if (idx < 16000) {
      int r = idx / 20, j2 = idx % 20;
      wl[j2 * 800 + r] = *(const uint2*)(Whh + (size_t)r * kH + 120 + 4 * j2);
    }
  }
  uint4 wr[15];
  if (tid < kG) {
    #pragma unroll
    for (int i = 0; i < 15; ++i)
      wr[i] = *(const uint4*)(Whh + (size_t)tid * kH + i * 8);
  }
  if (tid < 100) hpk[tid] = packh2(h0[2 * tid], h0[2 * tid + 1]);
  float c0 = 0.f, c1 = 0.f, hl0 = 0.f, hl1 = 0.f;
  f16 xcur = (f16)0;
  if (tid < kG) xcur = X[tid];
  __syncthreads();

  for (int t = 0; t < nsteps; ++t) {
    f16 xnext = (f16)0;
    if (tid < kG && t + 1 < nsteps) xnext = X[(size_t)(t + 1) * kG + tid];  // 1-step prefetch
    if (tid < kG) {
      float acc = (float)xcur;
      const uint4* hp4 = (const uint4*)hpk;
      #pragma unroll
      for (int i = 0; i < 15; ++i) {          // k 0..119 from registers
        uint4 hq = hp4[i];
        acc = fdot2f(wr[i].x, hq.x, acc);
        acc = fdot2f(wr[i].y, hq.y, acc);
        acc = fdot2f(wr[i].z, hq.z, acc);
        acc = fdot2f(wr[i].w, hq.w, acc);
      }
      #pragma unroll
      for (int i = 0; i < 10; ++i) {          // k 120..199 from LDS
        uint4 hq = hp4[15 + i];
        uint2 wa = wl[(2 * i) * 800 + tid];
        uint2 wb = wl[(2 * i + 1) * 800 + tid];
        acc = fdot2f(wa.x, hq.x, acc);
        acc = fdot2f(wa.y, hq.y, acc);
        acc = fdot2f(wb.x, hq.z, acc);
        acc = fdot2f(wb.y, hq.w, acc);
      }
      gsh[tid] = acc;
    }
    __syncthreads();
    if (tid < 100) {   // gate order i,f,g,o at offsets 0/200/400/600
      int n0 = 2 * tid, n1 = n0 + 1;
      float gi0 = gsh[n0],   gf0 = gsh[200 + n0], gg0 = gsh[400 + n0], go0 = gsh[600 + n0];
      float gi1 = gsh[n1],   gf1 = gsh[200 + n1], gg1 = gsh[400 + n1], go1 = gsh[600 + n1];
      c0 = sigf(gf0) * c0 + sigf(gi0) * tanhf_(gg0);
      hl0 = sigf(go0) * tanhf_(c0);
      c1 = sigf(gf1) * c1 + sigf(gi1) * tanhf_(gg1);
      hl1 = sigf(go1) * tanhf_(c1);
      hpk[tid] = packh2(hl0, hl1);
    }
    __syncthreads();
    xcur = xnext;
  }
  if (out != nullptr && tid < 100) {
    out[2 * tid] = hl0;
    out[2 * tid + 1] = hl1;
  }
}

// ---------------- wrappers ----------------
__global__ __launch_bounds__(NT) void ABHUE_lstm_batch(
    const f16* __restrict__ Xall, const f16* __restrict__ Wctx, const f16* __restrict__ Wmain,
    const float* __restrict__ h0s, float* __restrict__ sent)
{
  int s = blockIdx.x;                       // 0..254 ctx, 255 = main(mid)
  const f16* X = Xall + (size_t)s * kW * kG;
  const f16* Wh = (s == 255) ? Wmain : Wctx;
  int hrow = (s == 255) ? kMid : s;
  const float* h0 = h0s + (size_t)hrow * kH;
  float* out = (s == kMid) ? nullptr : sent + (size_t)hrow * kH;  // ctx[mid] discarded
  lstm_core(X, Wh, h0, kW, out);
}

__global__ __launch_bounds__(NT) void ABHUE_lstm_pp(
    const f16* __restrict__ Xpp, const f16* __restrict__ Wprev, const f16* __restrict__ Wpost,
    const float* __restrict__ h0prev, const float* __restrict__ h0post, float* __restrict__ outs)
{
  int s = blockIdx.x;   // 0 = prev, 1 = post
  lstm_core(Xpp + (size_t)s * 128 * kG, s ? Wpost : Wprev, s ? h0post : h0prev, 128, outs + s * kH);
}

__global__ __launch_bounds__(256) void ABHUE_fc(
    const float* __restrict__ feat, const float* __restrict__ fcW,
    const float* __restrict__ fcb, float* __restrict__ outp)
{
  __shared__ float fs[2 * kH];
  int tid = threadIdx.x;
  for (int i = tid; i < 2 * kH; i += 256) fs[i] = feat[i];
  __syncthreads();
  if (tid < kH) {
    float acc = fcb[tid];
    #pragma unroll 4
    for (int j = 0; j < 2 * kH; ++j) acc = fmaf(fcW[tid * 2 * kH + j], fs[j], acc);
    outp[tid] = acc;
  }
}

extern "C" void kernel_launch(void* const* d_in, const int* in_sizes, int n_in,
                              void* d_out, int out_size, void* d_ws, size_t ws_size,
                              hipStream_t stream) {
  const float* utt    = (const float*)d_in[0];
  const float* h0s    = (const float*)d_in[1];
  const float* h0prev = (const float*)d_in[2];
  const float* h0post = (const float*)d_in[3];
  const float* wih[4] = {(const float*)d_in[4],  (const float*)d_in[8],
                         (const float*)d_in[12], (const float*)d_in[16]};
  const float* whh[4] = {(const float*)d_in[5],  (const float*)d_in[9],
                         (const float*)d_in[13], (const float*)d_in[17]};
  const float* bih[4] = {(const float*)d_in[6],  (const float*)d_in[10],
                         (const float*)d_in[14], (const float*)d_in[18]};
  const float* bhh[4] = {(const float*)d_in[7],  (const float*)d_in[11],
                         (const float*)d_in[15], (const float*)d_in[19]};
  const float* fcW = (const float*)d_in[20];
  const float* fcb = (const float*)d_in[21];

  char* base  = (char*)d_ws;
  f16*   Xall = (f16*)base;                   // [131072 x 800] f16 (255*512 ctx rows + 512 main rows)
  f16*   Wf   = (f16*)(base + OFF_WF);        // slots: 0 ctxWih 1 ctxWhh 2 mainWih 3 mainWhh 4 prevWih 5 prevWhh 6 postWih 7 postWhh
  float* bsum = (float*)(base + OFF_BS);      // 0 ctx | 800 main | 1600 prev | 2400 post
  float* sent = (float*)(base + OFF_SENT);
  f16*   Xpp  = (f16*)(base + OFF_XPP);
  float* outs = (float*)(base + OFF_OUTS);

  const int WN = kG * kH;
  ABHUE_prep<<<(8 * WN + 4 * kG + 255) / 256, 256, 0, stream>>>(
      wih[0], whh[0], wih[1], whh[1], wih[2], whh[2], wih[3], whh[3],
      bih[0], bhh[0], bih[1], bhh[1], bih[2], bhh[2], bih[3], bhh[3],
      Wf, bsum);

  // ctx preactivations: 130560 rows
  ABHUE_gemm_x<<<2040, 256, 0, stream>>>(utt, Wf + 0 * WN, bsum + 0, Xall, -1);
  // main preactivations: 512 rows of sentence `mid`, placed at task slot 255
  ABHUE_gemm_x<<<8, 256, 0, stream>>>(utt + (size_t)kMid * kW * kH, Wf + 2 * WN,
                                      bsum + 800, Xall + (size_t)255 * kW * kG, -1);
  // 256 recurrences -> sentence embeddings
  ABHUE_lstm_batch<<<256, NT, 0, stream>>>(Xall, Wf + 1 * WN, Wf + 3 * WN, h0s, sent);
  // prev/post preactivations (post reads sent_emb reversed: row t <- sent[254-t])
  ABHUE_gemm_x<<<2, 256, 0, stream>>>(sent, Wf + 4 * WN, bsum + 1600, Xpp, -1);
  ABHUE_gemm_x<<<2, 256, 0, stream>>>(sent, Wf + 6 * WN, bsum + 2400, Xpp + (size_t)128 * kG, 254);
  // prev/post 128-step recurrences
  ABHUE_lstm_pp<<<2, NT, 0, stream>>>(Xpp, Wf + 5 * WN, Wf + 7 * WN, h0prev, h0post, outs);
  // final FC
  ABHUE_fc<<<1, 256, 0, stream>>>(outs, fcW, fcb, (float*)d_out);
}

// Round 3
// 1278.476 us; speedup vs baseline: 1.3164x; 1.3164x over previous
//
#include <hip/hip_runtime.h>
#include <hip/hip_fp16.h>
#include <cstdint>

typedef _Float16 f16;
typedef _Float16 f16x2 __attribute__((ext_vector_type(2)));
typedef _Float16 f16x4 __attribute__((ext_vector_type(4)));
typedef _Float16 f16x8 __attribute__((ext_vector_type(8)));
typedef float f32x4 __attribute__((ext_vector_type(4)));

#define kH 200
#define kG 800
#define kS 255
#define kW 512
#define kMid 127

// ---- ws layout (byte offsets), total ~213 MB ----
#define OFF_WF   209715200ULL   // 8 x [800x200] f16 weight matrices
#define OFF_BS   212275200ULL   // 4 x [800] f32 combined biases
#define OFF_SENT 212288000ULL   // [255x200] f32 sentence embeddings
#define OFF_XPP  212492032ULL   // 2 x [128x800] f16 prev/post preactivations
#define OFF_OUTS 212901632ULL   // [400] f32 prev_out|post_out

__device__ __forceinline__ float sigf(float x) { return 1.0f / (1.0f + __expf(-x)); }
__device__ __forceinline__ float tanhf_(float x) { return 1.0f - 2.0f / (__expf(2.0f * x) + 1.0f); }

// ---------------- prep: f32->f16 weights, combined biases ----------------
__global__ __launch_bounds__(256) void ABHUE_prep(
    const float* W0, const float* W1, const float* W2, const float* W3,
    const float* W4, const float* W5, const float* W6, const float* W7,
    const float* B0i, const float* B0h, const float* B1i, const float* B1h,
    const float* B2i, const float* B2h, const float* B3i, const float* B3h,
    f16* wdst, float* bdst)
{
  int idx = blockIdx.x * 256 + threadIdx.x;
  const int WN = kG * kH;  // 160000
  if (idx < 8 * WN) {
    int m = idx / WN, off = idx % WN;
    const float* src = m == 0 ? W0 : m == 1 ? W1 : m == 2 ? W2 : m == 3 ? W3
                     : m == 4 ? W4 : m == 5 ? W5 : m == 6 ? W6 : W7;
    wdst[idx] = (f16)src[off];
  } else {
    int j = idx - 8 * WN;
    if (j < 4 * kG) {
      int st = j / kG, k = j % kG;
      const float* bi = st == 0 ? B0i : st == 1 ? B1i : st == 2 ? B2i : B3i;
      const float* bh = st == 0 ? B0h : st == 1 ? B1h : st == 2 ? B2h : B3h;
      bdst[j] = bi[k] + bh[k];
    }
  }
}

// ---------------- GEMM: X[m, 0..799] = A[m,:200] @ W[800,200]^T + bias ----------------
#define BM 64
#define BKP 232
__global__ __launch_bounds__(256) void ABHUE_gemm_x(
    const float* __restrict__ A, const f16* __restrict__ Wf,
    const float* __restrict__ bias, f16* __restrict__ X, int rev)
{
  __shared__ __align__(16) f16 Al[BM * BKP];
  __shared__ __align__(16) f16 Bl[BM * BKP];
  int tid = threadIdx.x;
  int m0 = blockIdx.x * BM;

  #pragma unroll
  for (int it = 0; it < 4; ++it) {
    int idx = tid + 256 * it;
    int row = idx >> 4, dw = idx & 15;
    *(uint32_t*)(&Al[row * BKP + 200 + dw * 2]) = 0u;
    *(uint32_t*)(&Bl[row * BKP + 200 + dw * 2]) = 0u;
  }
  for (int it = 0; it < 13; ++it) {
    int q = tid + 256 * it;
    if (q < 3200) {
      int row = q / 50, c = q % 50;
      int rg = m0 + row; if (rev >= 0) rg = rev - rg;
      const float4 v = *(const float4*)(A + (size_t)rg * kH + c * 4);
      f16x2 p0; p0[0] = (f16)v.x; p0[1] = (f16)v.y;
      f16x2 p1; p1[0] = (f16)v.z; p1[1] = (f16)v.w;
      uint2 pk; pk.x = __builtin_bit_cast(uint32_t, p0); pk.y = __builtin_bit_cast(uint32_t, p1);
      *(uint2*)(&Al[row * BKP + c * 4]) = pk;
    }
  }
  int wv = tid >> 6, lane = tid & 63;
  int lr = lane & 15, lq = lane >> 4;

  for (int nt = 0; nt < 13; ++nt) {
    int n0 = nt * 64;
    __syncthreads();
    for (int it = 0; it < 7; ++it) {
      int q = tid + 256 * it;
      if (q < 1600) {
        int row = q / 25, c = q % 25;
        int ng = n0 + row;
        uint4 v = (ng < kG) ? *(const uint4*)(Wf + (size_t)ng * kH + c * 8)
                            : make_uint4(0, 0, 0, 0);
        *(uint4*)(&Bl[row * BKP + c * 8]) = v;
      }
    }
    __syncthreads();
    f32x4 acc0 = {0,0,0,0}, acc1 = {0,0,0,0}, acc2 = {0,0,0,0}, acc3 = {0,0,0,0};
    #pragma unroll
    for (int ks = 0; ks < 7; ++ks) {
      int k0 = ks * 32 + lq * 8;
      f16x8 a  = *(const f16x8*)(&Al[(wv * 16 + lr) * BKP + k0]);
      f16x8 b0 = *(const f16x8*)(&Bl[( 0 + lr) * BKP + k0]);
      f16x8 b1 = *(const f16x8*)(&Bl[(16 + lr) * BKP + k0]);
      f16x8 b2 = *(const f16x8*)(&Bl[(32 + lr) * BKP + k0]);
      f16x8 b3 = *(const f16x8*)(&Bl[(48 + lr) * BKP + k0]);
      acc0 = __builtin_amdgcn_mfma_f32_16x16x32_f16(a, b0, acc0, 0, 0, 0);
      acc1 = __builtin_amdgcn_mfma_f32_16x16x32_f16(a, b1, acc1, 0, 0, 0);
      acc2 = __builtin_amdgcn_mfma_f32_16x16x32_f16(a, b2, acc2, 0, 0, 0);
      acc3 = __builtin_amdgcn_mfma_f32_16x16x32_f16(a, b3, acc3, 0, 0, 0);
    }
    auto epi = [&](f32x4 acc, int nn) {
      int col = n0 + nn * 16 + lr;
      if (col < kG) {
        float bv = bias[col];
        #pragma unroll
        for (int rr = 0; rr < 4; ++rr) {
          int m = m0 + wv * 16 + lq * 4 + rr;
          X[(size_t)m * kG + col] = (f16)(acc[rr] + bv);
        }
      }
    };
    epi(acc0, 0); epi(acc1, 1); epi(acc2, 2); epi(acc3, 3);
  }
}

// ---------------- MFMA-ized sequential LSTM (one block = one sequence) ----------------
// K padded to 224 = 7 uniform 16x16x32 f16 MFMAs (no 16x16x16 tail).
// k-tile 6 (k=192..223): B real only in lq==0 lanes (wrow[192..199]); A reads
// h_lds[192..223] where [200,224) is zero. All fragment layouts identical to the
// (end-to-end verified) gemm_x kernel.
static __device__ void lstm_mfma(const f16* __restrict__ X, const f16* __restrict__ Whh,
                                 const float* __restrict__ h0, int nsteps,
                                 float* __restrict__ out)
{
  __shared__ __align__(16) f16 h_lds[224];
  __shared__ __align__(16) float gsh[kG];   // layout [unit][gate]: gsh[u*4+g]
  int tid = threadIdx.x;
  int lane = tid & 63, wv = tid >> 6;
  int lr = lane & 15, lq = lane >> 4;
  int t0 = (50 * wv) >> 3;
  int cnt = ((50 * (wv + 1)) >> 3) - t0;

  // ---- load B-fragments (persistent in VGPRs) ----
  f16x8 bf[7][7];
  #pragma unroll
  for (int i = 0; i < 7; ++i) {
    if (i < cnt) {
      int n = (t0 + i) * 16 + lr;
      const f16* wrow = Whh + (size_t)n * kH;
      #pragma unroll
      for (int kt = 0; kt < 6; ++kt)
        bf[i][kt] = *(const f16x8*)(wrow + kt * 32 + lq * 8);
      bf[i][6] = (lq == 0) ? *(const f16x8*)(wrow + 192)
                           : (f16x8){0,0,0,0,0,0,0,0};
    }
  }

  // ---- A-fragments: only lanes lr==0 carry data (M=1); others stay zero ----
  f16x8 af[7];
  #pragma unroll
  for (int kt = 0; kt < 7; ++kt) af[kt] = (f16x8){0,0,0,0,0,0,0,0};

  if (tid < kH) h_lds[tid] = (f16)h0[tid];
  if (tid >= kH && tid < 224) h_lds[tid] = (f16)0;

  float cst = 0.f, hout = 0.f;
  f16 xc0 = (f16)0, xc1 = (f16)0, xc2 = (f16)0, xc3 = (f16)0;
  if (tid < kH) {
    xc0 = X[tid]; xc1 = X[kH + tid]; xc2 = X[2 * kH + tid]; xc3 = X[3 * kH + tid];
  }
  __syncthreads();

  for (int t = 0; t < nsteps; ++t) {
    // prefetch next step's X (VMEM, overlaps MFMA phase)
    f16 xn0 = (f16)0, xn1 = (f16)0, xn2 = (f16)0, xn3 = (f16)0;
    if (tid < kH && t + 1 < nsteps) {
      const f16* Xn = X + (size_t)(t + 1) * kG;
      xn0 = Xn[tid]; xn1 = Xn[kH + tid]; xn2 = Xn[2 * kH + tid]; xn3 = Xn[3 * kH + tid];
    }
    // A-fragment read: 4 lanes/wave, 7 LDS instrs
    if (lr == 0) {
      #pragma unroll
      for (int kt = 0; kt < 7; ++kt)
        af[kt] = *(const f16x8*)(h_lds + kt * 32 + lq * 8);
    }
    // MFMA over my N-tiles, acc recycled per tile
    #pragma unroll
    for (int i = 0; i < 7; ++i) {
      if (i < cnt) {
        f32x4 acc = {0.f, 0.f, 0.f, 0.f};
        #pragma unroll
        for (int kt = 0; kt < 7; ++kt)
          acc = __builtin_amdgcn_mfma_f32_16x16x32_f16(af[kt], bf[i][kt], acc, 0, 0, 0);
        if (lane < 16) {                       // D row 0 lives in acc[0] of lanes 0-15
          int n = (t0 + i) * 16 + lane;
          int g = n / kH, u = n - g * kH;
          gsh[u * 4 + g] = acc[0];
        }
      }
    }
    __syncthreads();
    // cell update on 200 threads
    if (tid < kH) {
      float4 gv = *(const float4*)(gsh + tid * 4);
      float gi = gv.x + (float)xc0;
      float gf = gv.y + (float)xc1;
      float gg = gv.z + (float)xc2;
      float go = gv.w + (float)xc3;
      cst  = sigf(gf) * cst + sigf(gi) * tanhf_(gg);
      hout = sigf(go) * tanhf_(cst);
      h_lds[tid] = (f16)hout;
    }
    xc0 = xn0; xc1 = xn1; xc2 = xn2; xc3 = xn3;
    __syncthreads();
  }
  if (out != nullptr && tid < kH) out[tid] = hout;
}

// ---------------- wrappers ----------------
__global__ __launch_bounds__(512, 2) void ABHUE_lstm_batch(
    const f16* __restrict__ Xall, const f16* __restrict__ Wctx, const f16* __restrict__ Wmain,
    const float* __restrict__ h0s, float* __restrict__ sent)
{
  int s = blockIdx.x;                       // 0..254 ctx, 255 = main(mid)
  const f16* X = Xall + (size_t)s * kW * kG;
  const f16* Wh = (s == 255) ? Wmain : Wctx;
  int hrow = (s == 255) ? kMid : s;
  const float* h0 = h0s + (size_t)hrow * kH;
  float* out = (s == kMid) ? nullptr : sent + (size_t)hrow * kH;  // ctx[mid] discarded
  lstm_mfma(X, Wh, h0, kW, out);
}

__global__ __launch_bounds__(512, 2) void ABHUE_lstm_pp(
    const f16* __restrict__ Xpp, const f16* __restrict__ Wprev, const f16* __restrict__ Wpost,
    const float* __restrict__ h0prev, const float* __restrict__ h0post, float* __restrict__ outs)
{
  int s = blockIdx.x;   // 0 = prev, 1 = post
  lstm_mfma(Xpp + (size_t)s * 128 * kG, s ? Wpost : Wprev, s ? h0post : h0prev, 128, outs + s * kH);
}

__global__ __launch_bounds__(256) void ABHUE_fc(
    const float* __restrict__ feat, const float* __restrict__ fcW,
    const float* __restrict__ fcb, float* __restrict__ outp)
{
  __shared__ float fs[2 * kH];
  int tid = threadIdx.x;
  for (int i = tid; i < 2 * kH; i += 256) fs[i] = feat[i];
  __syncthreads();
  if (tid < kH) {
    float acc = fcb[tid];
    #pragma unroll 4
    for (int j = 0; j < 2 * kH; ++j) acc = fmaf(fcW[tid * 2 * kH + j], fs[j], acc);
    outp[tid] = acc;
  }
}

extern "C" void kernel_launch(void* const* d_in, const int* in_sizes, int n_in,
                              void* d_out, int out_size, void* d_ws, size_t ws_size,
                              hipStream_t stream) {
  const float* utt    = (const float*)d_in[0];
  const float* h0s    = (const float*)d_in[1];
  const float* h0prev = (const float*)d_in[2];
  const float* h0post = (const float*)d_in[3];
  const float* wih[4] = {(const float*)d_in[4],  (const float*)d_in[8],
                         (const float*)d_in[12], (const float*)d_in[16]};
  const float* whh[4] = {(const float*)d_in[5],  (const float*)d_in[9],
                         (const float*)d_in[13], (const float*)d_in[17]};
  const float* bih[4] = {(const float*)d_in[6],  (const float*)d_in[10],
                         (const float*)d_in[14], (const float*)d_in[18]};
  const float* bhh[4] = {(const float*)d_in[7],  (const float*)d_in[11],
                         (const float*)d_in[15], (const float*)d_in[19]};
  const float* fcW = (const float*)d_in[20];
  const float* fcb = (const float*)d_in[21];

  char* base  = (char*)d_ws;
  f16*   Xall = (f16*)base;                   // [131072 x 800] f16
  f16*   Wf   = (f16*)(base + OFF_WF);
  float* bsum = (float*)(base + OFF_BS);
  float* sent = (float*)(base + OFF_SENT);
  f16*   Xpp  = (f16*)(base + OFF_XPP);
  float* outs = (float*)(base + OFF_OUTS);

  const int WN = kG * kH;
  ABHUE_prep<<<(8 * WN + 4 * kG + 255) / 256, 256, 0, stream>>>(
      wih[0], whh[0], wih[1], whh[1], wih[2], whh[2], wih[3], whh[3],
      bih[0], bhh[0], bih[1], bhh[1], bih[2], bhh[2], bih[3], bhh[3],
      Wf, bsum);

  ABHUE_gemm_x<<<2040, 256, 0, stream>>>(utt, Wf + 0 * WN, bsum + 0, Xall, -1);
  ABHUE_gemm_x<<<8, 256, 0, stream>>>(utt + (size_t)kMid * kW * kH, Wf + 2 * WN,
                                      bsum + 800, Xall + (size_t)255 * kW * kG, -1);
  ABHUE_lstm_batch<<<256, 512, 0, stream>>>(Xall, Wf + 1 * WN, Wf + 3 * WN, h0s, sent);
  ABHUE_gemm_x<<<2, 256, 0, stream>>>(sent, Wf + 4 * WN, bsum + 1600, Xpp, -1);
  ABHUE_gemm_x<<<2, 256, 0, stream>>>(sent, Wf + 6 * WN, bsum + 2400, Xpp + (size_t)128 * kG, 254);
  ABHUE_lstm_pp<<<2, 512, 0, stream>>>(Xpp, Wf + 5 * WN, Wf + 7 * WN, h0prev, h0post, outs);
  ABHUE_fc<<<1, 256, 0, stream>>>(outs, fcW, fcb, (float*)d_out);
}